// Round 7
// baseline (1541.841 us; speedup 1.0000x reference)
//
#include <hip/hip_runtime.h>
#include <stdint.h>

#define TT 96
#define SS 1024
#define BB 256
#define START_TAG 94
#define STOP_TAG 95
#define LOG2E 1.44269504088896340736f
#define LN2   0.69314718055994530942f

typedef float f32x2 __attribute__((ext_vector_type(2)));
typedef float f32x4v __attribute__((ext_vector_type(4)));
typedef __bf16 bf16x8 __attribute__((ext_vector_type(8)));

// ---- fat-path ws layout (bytes) ----
#define EF_BYTES   50331648u          // 16 grp * 1024 t * 3072 B
#define ABUF_OFF   50331648u
#define ESTART_OFF 50350080u
#define ESTOP_OFF  50356224u
#define WS_NEED    50427904u

union U4B { uint4 u; bf16x8 v; };

static __device__ __forceinline__ uint32_t pk_bf16(float a, float b) {
    uint32_t r;
    asm("v_cvt_pk_bf16_f32 %0, %1, %2" : "=v"(r) : "v"(a), "v"(b));
    return r;
}
static __device__ __forceinline__ f32x2 pmax2(f32x2 a, f32x2 b) {
#if __has_builtin(__builtin_elementwise_max)
    return __builtin_elementwise_max(a, b);
#else
    f32x2 r; r.x = fmaxf(a.x, b.x); r.y = fmaxf(a.y, b.y); return r;
#endif
}

#define MFMA(a, b, c) __builtin_amdgcn_mfma_f32_16x16x32_bf16((a), (b), (c), 0, 0, 0)
#define GLD(srcp, dstp) __builtin_amdgcn_global_load_lds( \
    (const __attribute__((address_space(1))) uint32_t*)(srcp), \
    (__attribute__((address_space(3))) uint32_t*)(dstp), 16, 0, 0)

// ---------------------------------------------------------------------------
// prep_consts (verified): A-fragments of E^T (bf16, MFMA lane order) +
// Estart/Estop in D-layout lane order.
// ---------------------------------------------------------------------------
__global__ __launch_bounds__(256) void prep_consts(const float* __restrict__ tr,
                                                   char* __restrict__ ws) {
    int i = blockIdx.x * 256 + threadIdx.x;
    if (i < 4608) {
        uint32_t* A = (uint32_t*)(ws + ABUF_OFF);
        int tile = i >> 8, rem = i & 255, l = rem >> 2, v = rem & 3;
        int mt = tile / 3, kt = tile - mt * 3;
        int hi = l >> 4, m = 16 * mt + (l & 15);
        int k0 = 32 * kt + 16 * (v >> 1) + 4 * hi + 2 * (v & 1);
        A[i] = pk_bf16(expf(tr[k0 * TT + m]), expf(tr[(k0 + 1) * TT + m]));
    } else if (i < 4608 + 2 * 1536) {
        int e = i - 4608;
        int stop = (e >= 1536) ? 1 : 0;
        if (stop) e -= 1536;
        int l = e / 24, c = e % 24;
        int mt = c >> 2, r = c & 3, hi = l >> 4;
        int j = 16 * mt + 4 * hi + r;
        float* dst = (float*)(ws + (stop ? ESTOP_OFF : ESTART_OFF));
        dst[e] = expf(stop ? tr[j * TT + STOP_TAG] : tr[START_TAG * TT + j]);
    }
}

// ---------------------------------------------------------------------------
// ef_kernel2 (verified): float4 in, uint2 out.
// ---------------------------------------------------------------------------
__global__ __launch_bounds__(256) void ef_kernel2(const float* __restrict__ f,
                                                  uint32_t* __restrict__ ef) {
    int tid = blockIdx.x * 256 + threadIdx.x;   // exact: 16*1024*64*6
    int p   = tid % 6;
    int r   = tid / 6;
    int l   = r & 63;
    int bt  = r >> 6;
    int t   = bt & 1023;
    int blk = bt >> 10;
    int b   = blk * 16 + (l & 15);
    int hi  = l >> 4;
    const float4* fp = (const float4*)(f + (size_t)(b * SS + t) * TT + 16 * p + 4 * hi);
    float4 v = *fp;
    uint2 w;
    w.x = pk_bf16(expf(v.x), expf(v.y));
    w.y = pk_bf16(expf(v.z), expf(v.w));
    *(uint2*)(ef + (size_t)r * 12 + 2 * p) = w;
}

// ---------------------------------------------------------------------------
// fwd_kernel: blocks 0..3 = MFMA scan, 4 independent chains per wave
// (latency hiding via cross-chain ILP). blocks 4..255 = gold score.
// ---------------------------------------------------------------------------
__global__ __launch_bounds__(64, 1) void fwd_kernel(
    const float* __restrict__ features, const int* __restrict__ mask,
    const int* __restrict__ y, const float* __restrict__ trans,
    const char* __restrict__ ws, float* __restrict__ out)
{
    const int l = threadIdx.x;

    if (blockIdx.x >= 4) {
        // ---------------- gold part ----------------
        int bg = blockIdx.x - 4;
        float e = 0.f;
        #pragma unroll 1
        for (int k = 0; k < 17; ++k) {
            int idx = bg * 64 + l + k * 16128;
            if (idx < BB * SS) {
                int t = idx & (SS - 1);
                if (mask[idx]) {
                    int yt   = y[idx];
                    int prev = t ? y[idx - 1] : START_TAG;
                    e += features[(size_t)idx * TT + yt] + trans[prev * TT + yt];
                    bool last = (t == SS - 1) || (mask[idx + 1] == 0);
                    if (last) e += trans[yt * TT + STOP_TAG];
                }
            }
        }
        #pragma unroll
        for (int d = 1; d < 64; d <<= 1) e += __shfl_xor(e, d);
        if (l == 0) atomicAdd(out, -e);
        return;
    }

    __shared__ __align__(16) char ring[4 * 8 * 3072];   // 96 KiB
    char* ringc = (char*)ring;

    const int blk4 = blockIdx.x * 4;   // first batch-group of this block
    const int n = l & 15, hi = l >> 4;

    // ---- per-chain length ----
    int len_m1[4];
    #pragma unroll
    for (int c = 0; c < 4; ++c) {
        int cnt = 0;
        const int4* mrow = (const int4*)(mask + ((blk4 + c) * 16 + n) * SS + 512 + hi * 128);
        #pragma unroll
        for (int k = 0; k < 32; ++k) {
            int4 mv = mrow[k];
            cnt += mv.x + mv.y + mv.z + mv.w;
        }
        cnt += __shfl_xor(cnt, 16);
        cnt += __shfl_xor(cnt, 32);
        len_m1[c] = cnt + 511;
    }

    // ---- shared constants ----
    bf16x8 Af[6][3];
    {
        const uint4* ab = (const uint4*)(ws + ABUF_OFF);
        #pragma unroll
        for (int mt = 0; mt < 6; ++mt)
            #pragma unroll
            for (int kt = 0; kt < 3; ++kt) {
                U4B ub; ub.u = ab[(mt * 3 + kt) * 64 + l];
                Af[mt][kt] = ub.v;
            }
    }
    f32x2 estL[6], estH[6];
    {
        const float4* es1 = (const float4*)(ws + ESTOP_OFF);
        #pragma unroll
        for (int mt = 0; mt < 6; ++mt) {
            float4 v = es1[l * 6 + mt];
            estL[mt].x = v.x; estL[mt].y = v.y;
            estH[mt].x = v.z; estH[mt].y = v.w;
        }
    }

    // ---- DMA prologue: slots 0..3 for all 4 chains ----
    const char* efg[4];
    #pragma unroll
    for (int c = 0; c < 4; ++c)
        efg[c] = ws + (size_t)(blk4 + c) * SS * 3072 + l * 16;

    #pragma unroll
    for (int s = 0; s < 4; ++s)
        #pragma unroll
        for (int c = 0; c < 4; ++c) {
            const char* sp = efg[c] + s * 3072;
            char* dp = ringc + c * 24576 + s * 3072;
            GLD(sp, dp); GLD(sp + 1024, dp + 1024); GLD(sp + 2048, dp + 2048);
        }
    asm volatile("s_waitcnt vmcnt(0)" ::: "memory");

    // ---- per-chain state ----
    float c2[4], pe[4], logz[4];
    f32x2 pend2[4];
    bf16x8 Bf[4][3];
    uint4 PA[4][3];
    const f32x4v Z4 = {0.f, 0.f, 0.f, 0.f};

#define UNPACKP(PBUF, EFP) { \
    uint32_t w_[12] = { PBUF[0].x, PBUF[0].y, PBUF[0].z, PBUF[0].w, \
                        PBUF[1].x, PBUF[1].y, PBUF[1].z, PBUF[1].w, \
                        PBUF[2].x, PBUF[2].y, PBUF[2].z, PBUF[2].w }; \
    _Pragma("unroll") \
    for (int q_ = 0; q_ < 12; ++q_) { \
        EFP[q_ >> 1][q_ & 1].x = __uint_as_float(w_[q_] << 16); \
        EFP[q_ >> 1][q_ & 1].y = __uint_as_float(w_[q_] & 0xffff0000u); \
    } }

#define PACKB2(AFL, AFH, BDST) { \
    uint32_t wlo_[6], whi_[6]; \
    _Pragma("unroll") \
    for (int mt_ = 0; mt_ < 6; ++mt_) { \
        wlo_[mt_] = pk_bf16(AFL[mt_].x, AFL[mt_].y); \
        whi_[mt_] = pk_bf16(AFH[mt_].x, AFH[mt_].y); } \
    _Pragma("unroll") \
    for (int kt_ = 0; kt_ < 3; ++kt_) { \
        U4B ub_; ub_.u.x = wlo_[2 * kt_]; ub_.u.y = whi_[2 * kt_]; \
        ub_.u.z = wlo_[2 * kt_ + 1]; ub_.u.w = whi_[2 * kt_ + 1]; \
        BDST[kt_] = ub_.v; } }

    // ---- init t = 0 per chain: alpha0 = EF0 * Estart; prefetch slot 1 -> PA ----
    {
        f32x2 esrL[6], esrH[6];
        const float4* es0 = (const float4*)(ws + ESTART_OFF);
        #pragma unroll
        for (int mt = 0; mt < 6; ++mt) {
            float4 v = es0[l * 6 + mt];
            esrL[mt].x = v.x; esrL[mt].y = v.y;
            esrH[mt].x = v.z; esrH[mt].y = v.w;
        }
        #pragma unroll
        for (int c = 0; c < 4; ++c) {
            uint4 T[3];
            const uint4* rp = (const uint4*)(ringc + c * 24576 + l * 48);
            T[0] = rp[0]; T[1] = rp[1]; T[2] = rp[2];
            f32x2 efp[6][2];
            UNPACKP(T, efp);
            f32x2 afL[6], afH[6];
            #pragma unroll
            for (int mt = 0; mt < 6; ++mt) {
                afL[mt] = efp[mt][0] * esrL[mt];
                afH[mt] = efp[mt][1] * esrH[mt];
            }
            PACKB2(afL, afH, Bf[c]);
            const uint4* rq = (const uint4*)(ringc + c * 24576 + 3072 + l * 48);
            PA[c][0] = rq[0]; PA[c][1] = rq[1]; PA[c][2] = rq[2];
            c2[c] = 0.f; pe[c] = 0.f; logz[c] = 0.f;
            pend2[c].x = 1.f; pend2[c].y = 1.f;
        }
    }

// One superstep: advance all 4 chains by one time-step t_.
// GLD slot t+3 (all chains) -> wait vmcnt(24) (slot t+1 complete) ->
// per chain: MFMA, unpack EF_t, af, ds_read slot t+1 -> PA, pack Bf, cap, renorm.
#define SUPER(T, APPLY, ARED) { \
    const int t_ = (T); \
    { int ts_ = t_ + 3; if (ts_ > 1023) ts_ = 1023; \
      _Pragma("unroll") \
      for (int c_ = 0; c_ < 4; ++c_) { \
          const char* sp_ = efg[c_] + (size_t)ts_ * 3072; \
          char* dp_ = ringc + c_ * 24576 + ((t_ + 3) & 7) * 3072; \
          GLD(sp_, dp_); GLD(sp_ + 1024, dp_ + 1024); GLD(sp_ + 2048, dp_ + 2048); } } \
    asm volatile("s_waitcnt vmcnt(24)" ::: "memory"); \
    _Pragma("unroll") \
    for (int c_ = 0; c_ < 4; ++c_) { \
        f32x4v acc[6]; \
        _Pragma("unroll") \
        for (int mt_ = 0; mt_ < 6; ++mt_) { \
            acc[mt_] = MFMA(Af[mt_][0], Bf[c_][0], Z4); \
            acc[mt_] = MFMA(Af[mt_][1], Bf[c_][1], acc[mt_]); \
            acc[mt_] = MFMA(Af[mt_][2], Bf[c_][2], acc[mt_]); } \
        f32x2 efp[6][2]; \
        UNPACKP(PA[c_], efp); \
        f32x2 afL[6], afH[6]; \
        _Pragma("unroll") \
        for (int mt_ = 0; mt_ < 6; ++mt_) { \
            f32x2 aL_, aH_; \
            aL_.x = acc[mt_][0]; aL_.y = acc[mt_][1]; \
            aH_.x = acc[mt_][2]; aH_.y = acc[mt_][3]; \
            if (APPLY) { aL_ = aL_ * pend2[c_]; aH_ = aH_ * pend2[c_]; } \
            afL[mt_] = aL_ * efp[mt_][0]; \
            afH[mt_] = aH_ * efp[mt_][1]; } \
        if (APPLY) { c2[c_] += pe[c_]; } \
        { const uint4* rp_ = (const uint4*)(ringc + c_ * 24576 + ((t_ + 1) & 7) * 3072 + l * 48); \
          PA[c_][0] = rp_[0]; PA[c_][1] = rp_[1]; PA[c_][2] = rp_[2]; } \
        PACKB2(afL, afH, Bf[c_]); \
        { int cap_ = (len_m1[c_] == t_); \
          if (__any(cap_)) { \
              f32x2 ds_ = afL[0] * estL[0]; \
              ds_ = ds_ + afH[0] * estH[0]; \
              _Pragma("unroll") \
              for (int mt_ = 1; mt_ < 6; ++mt_) { \
                  ds_ = ds_ + afL[mt_] * estL[mt_]; \
                  ds_ = ds_ + afH[mt_] * estH[mt_]; } \
              float dd_ = ds_.x + ds_.y; \
              dd_ += __shfl_xor(dd_, 16); dd_ += __shfl_xor(dd_, 32); \
              float lz_ = LN2 * (c2[c_] + log2f(dd_)); \
              logz[c_] = cap_ ? lz_ : logz[c_]; } } \
        if (ARED) { \
            f32x2 mp_ = pmax2(afL[0], afH[0]); \
            _Pragma("unroll") \
            for (int mt_ = 1; mt_ < 6; ++mt_) \
                mp_ = pmax2(mp_, pmax2(afL[mt_], afH[mt_])); \
            float mm_ = fmaxf(mp_.x, mp_.y); \
            mm_ = fmaxf(mm_, __shfl_xor(mm_, 16)); \
            mm_ = fmaxf(mm_, __shfl_xor(mm_, 32)); \
            unsigned eb_ = (__float_as_uint(mm_) >> 23) & 255u; \
            pe[c_] = (float)((int)eb_ - 127); \
            float pn_ = __uint_as_float((254u - eb_) << 23); \
            pend2[c_].x = pn_; pend2[c_].y = pn_; } \
    } }

    // head supersteps t = 1,2,3 (cadence: APPLY at t%4==1, ARED at t%4==3)
    SUPER(1, 1, 0)
    SUPER(2, 0, 0)
    SUPER(3, 0, 1)
    #pragma unroll 1
    for (int tb = 1; tb < 256; ++tb) {
        const int t4 = tb * 4;
        SUPER(t4 + 0, 0, 0)
        SUPER(t4 + 1, 1, 0)
        SUPER(t4 + 2, 0, 0)
        SUPER(t4 + 3, 0, 1)
    }

    float s = logz[0] + logz[1] + logz[2] + logz[3];
    if (l < 16) atomicAdd(out, s);
#undef SUPER
#undef PACKB2
#undef UNPACKP
}

// ===========================================================================
// Fallback path (ws too small): R1's verified kernels.
// ===========================================================================
__global__ void fb_prep(const float* __restrict__ trans, float* __restrict__ E2T) {
    int idx = blockIdx.x * blockDim.x + threadIdx.x;
    if (idx < TT * TT) {
        int jj = idx / TT, ii = idx % TT;
        E2T[idx] = expf(trans[ii * TT + jj]);
    }
}

__global__ __launch_bounds__(384) void fb_forward(
    const float* __restrict__ features, const int* __restrict__ mask,
    const float* __restrict__ trans, const float* __restrict__ E2T,
    float* __restrict__ out)
{
    const int b    = blockIdx.x;
    const int tid  = threadIdx.x;
    const int j    = tid >> 2;
    const int q    = tid & 3;
    const int lane = tid & 63;
    const int wv   = tid >> 6;

    __shared__ float alpha[2][TT];
    __shared__ float fch[2][16 * TT];
    __shared__ float wred[6];
    __shared__ int   wcnt[6];
    __shared__ int   len_sh;

    int cnt = 0;
    for (int i = tid; i < SS; i += 384) cnt += (mask[b * SS + i] != 0);
    #pragma unroll
    for (int d = 1; d < 64; d <<= 1) cnt += __shfl_xor(cnt, d);
    if (lane == 0) wcnt[wv] = cnt;
    __syncthreads();
    if (tid == 0) {
        int L = 0;
        for (int w = 0; w < 6; ++w) L += wcnt[w];
        len_sh = L;
    }

    float Er[24];
    {
        const float4* ep = reinterpret_cast<const float4*>(E2T + j * TT + q * 24);
        #pragma unroll
        for (int k = 0; k < 6; ++k) {
            float4 e4 = ep[k];
            Er[4*k+0] = e4.x; Er[4*k+1] = e4.y; Er[4*k+2] = e4.z; Er[4*k+3] = e4.w;
        }
    }

    const float* fb = features + (size_t)b * SS * TT;
    float4 r0    = reinterpret_cast<const float4*>(fb)[tid];
    float4 rnext = reinterpret_cast<const float4*>(fb + 16 * TT)[tid];
    reinterpret_cast<float4*>(&fch[0][0])[tid] = r0;
    __syncthreads();
    const int len = len_sh;

    if (q == 0) {
        float p0 = fch[0][j] + trans[START_TAG * TT + j];
        alpha[0][j] = exp2f(p0 * LOG2E);
    }
    __syncthreads();

    float c2 = 0.0f;
    float pending = 1.0f;
    int   pe = 0;

    const int clast = (len - 1) >> 4;
    for (int c = 0; c <= clast; ++c) {
        if (c > 0) {
            reinterpret_cast<float4*>(&fch[c & 1][0])[tid] = rnext;
            int cn = c + 1; if (cn > SS / 16 - 1) cn = SS / 16 - 1;
            rnext = reinterpret_cast<const float4*>(fb + cn * 16 * TT)[tid];
            __syncthreads();
        }
        const int t0   = c * 16;
        const int tbeg = (c == 0) ? 1 : t0;
        int tend = t0 + 16; if (tend > len) tend = len;

        for (int t = tbeg; t < tend; ++t) {
            const float* acur = alpha[(t + 1) & 1];
            const float4* ap = reinterpret_cast<const float4*>(acur + q * 24);
            float sum = 0.0f;
            #pragma unroll
            for (int k = 0; k < 6; ++k) {
                float4 a = ap[k];
                sum = fmaf(Er[4*k+0], a.x, sum);
                sum = fmaf(Er[4*k+1], a.y, sum);
                sum = fmaf(Er[4*k+2], a.z, sum);
                sum = fmaf(Er[4*k+3], a.w, sum);
            }
            sum += __shfl_xor(sum, 1);
            sum += __shfl_xor(sum, 2);

            float f    = fch[c & 1][(t - t0) * TT + j];
            float anew = sum * exp2f(f * LOG2E) * pending;
            c2 += (float)pe; pe = 0; pending = 1.0f;

            if (q == 0) alpha[t & 1][j] = anew;
            if ((t & 3) == 3) {
                float m = anew;
                m = fmaxf(m, __shfl_xor(m, 4));
                m = fmaxf(m, __shfl_xor(m, 8));
                m = fmaxf(m, __shfl_xor(m, 16));
                m = fmaxf(m, __shfl_xor(m, 32));
                if (lane == 0) wred[wv] = m;
            }
            __syncthreads();
            if ((t & 3) == 3) {
                float mv = wred[0];
                #pragma unroll
                for (int w = 1; w < 6; ++w) mv = fmaxf(mv, wred[w]);
                int eb  = (int)((__float_as_uint(mv) >> 23) & 255u);
                pe      = eb - 127;
                pending = __uint_as_float((uint32_t)(254 - eb) << 23);
            }
        }
    }

    float v = 0.0f;
    if (q == 0) v = alpha[(len - 1) & 1][j] * E2T[STOP_TAG * TT + j];
    #pragma unroll
    for (int d = 1; d < 64; d <<= 1) v += __shfl_xor(v, d);
    __syncthreads();
    if (lane == 0) wred[wv] = v;
    __syncthreads();
    if (tid == 0) {
        float tot = 0.0f;
        for (int w = 0; w < 6; ++w) tot += wred[w];
        atomicAdd(out, LN2 * (c2 + log2f(tot)));
    }
}

__global__ void fb_gold(const float* __restrict__ features, const int* __restrict__ mask,
                        const int* __restrict__ y, const float* __restrict__ trans,
                        float* __restrict__ out)
{
    int idx = blockIdx.x * blockDim.x + threadIdx.x;
    float e = 0.0f;
    if (idx < BB * SS) {
        int t = idx % SS;
        if (mask[idx] != 0) {
            int yt   = y[idx];
            int prev = (t == 0) ? START_TAG : y[idx - 1];
            e = features[(size_t)idx * TT + yt] + trans[prev * TT + yt];
            bool is_last = (t == SS - 1) || (mask[idx + 1] == 0);
            if (is_last) e += trans[yt * TT + STOP_TAG];
        }
    }
    #pragma unroll
    for (int d = 1; d < 64; d <<= 1) e += __shfl_xor(e, d);
    __shared__ float ws4[4];
    int lane = threadIdx.x & 63, wv = threadIdx.x >> 6;
    if (lane == 0) ws4[wv] = e;
    __syncthreads();
    if (threadIdx.x == 0) {
        float s = ws4[0] + ws4[1] + ws4[2] + ws4[3];
        atomicAdd(out, -s);
    }
}

extern "C" void kernel_launch(void* const* d_in, const int* in_sizes, int n_in,
                              void* d_out, int out_size, void* d_ws, size_t ws_size,
                              hipStream_t stream) {
    const float* features = (const float*)d_in[0];
    const int*   mask     = (const int*)d_in[1];
    const int*   y        = (const int*)d_in[2];
    const float* trans    = (const float*)d_in[3];
    float*       out      = (float*)d_out;

    hipMemsetAsync(d_out, 0, sizeof(float) * out_size, stream);

    if (ws_size >= WS_NEED) {
        char* ws = (char*)d_ws;
        prep_consts<<<30, 256, 0, stream>>>(trans, ws);
        ef_kernel2<<<24576, 256, 0, stream>>>(features, (uint32_t*)ws);
        fwd_kernel<<<256, 64, 0, stream>>>(features, mask, y, trans, ws, out);
    } else {
        float* E2T = (float*)d_ws;
        fb_prep<<<(TT * TT + 255) / 256, 256, 0, stream>>>(trans, E2T);
        fb_forward<<<BB, 384, 0, stream>>>(features, mask, trans, E2T, out);
        fb_gold<<<(BB * SS) / 256, 256, 0, stream>>>(features, mask, y, trans, out);
    }
}